// Round 14
// baseline (1480.712 us; speedup 1.0000x reference)
//
#include <hip/hip_runtime.h>

// ---------------------------------------------------------------------------
// BiLSTM tagger: emb -> [fwd LSTM, batch-flipped copy] x2 -> FC -> log_softmax
// B=64, T=256, V=50000, E=256, H=512, O=50. Gate dim G=4H=2048.
//
// R14 = R13 + single-barrier scan steps (L1/L2S):
//   Wave layout: each wave owns 8 units x ALL 4 gates (tile0 = gates{i,f},
//   tile1 = gates{g,o}) -> gate exchange is 2 intra-wave shfl_xor(8)s.
//   glds + barrier2 deleted; hl double-buffered (hl2[2][16][520]) so the one
//   barrier separates stage-writes from MFMA-reads. Sentinels re-derived:
//   L1 mysent unchanged (t+1 after elementwise; consumer waits t+2 => next
//   barrier's vmcnt drain passed). L2S prog delayed one step (published
//   after barrier(t) => step t-1 ring reads drained). G2 byte-identical R13.
// ---------------------------------------------------------------------------

#define B_ 64
#define T_ 256
#define E_ 256
#define H_ 512
#define G_ 2048
#define O_ 50
#define NROW (B_ * T_)   // 16384
#define RING 16

typedef unsigned short u16;
typedef unsigned int u32;
typedef unsigned long long u64;
typedef short bf16x8 __attribute__((ext_vector_type(8)));
typedef u16 u16x4 __attribute__((ext_vector_type(4)));
typedef u32 u32x4 __attribute__((ext_vector_type(4)));
typedef float f32x4 __attribute__((ext_vector_type(4)));

#define LD_AG(p)    __hip_atomic_load((p), __ATOMIC_RELAXED, __HIP_MEMORY_SCOPE_AGENT)
#define ST_AG(p, v) __hip_atomic_store((p), (v), __ATOMIC_RELAXED, __HIP_MEMORY_SCOPE_AGENT)

__device__ __forceinline__ u16 f2bf(float f) {
    unsigned u = __float_as_uint(f);
    return (u16)((u + 0x7fffu + ((u >> 16) & 1u)) >> 16);
}
__device__ __forceinline__ float bf2f(u16 x) {
    return __uint_as_float(((u32)x) << 16);
}
__device__ __forceinline__ float sigm(float x) {
    x = fminf(fmaxf(x, -30.f), 30.f);
    return 1.f / (1.f + __expf(-x));
}
__device__ __forceinline__ float tanh_f(float x) {
    x = fminf(fmaxf(x, -15.f), 15.f);
    float e = __expf(2.f * x);
    return (e - 1.f) / (e + 1.f);
}
__device__ __forceinline__ bf16x8 pack8(const float* p) {
    float4 v0 = *(const float4*)p;
    float4 v1 = *(const float4*)(p + 4);
    bf16x8 bb;
    bb[0] = (short)f2bf(v0.x); bb[1] = (short)f2bf(v0.y);
    bb[2] = (short)f2bf(v0.z); bb[3] = (short)f2bf(v0.w);
    bb[4] = (short)f2bf(v1.x); bb[5] = (short)f2bf(v1.y);
    bb[6] = (short)f2bf(v1.z); bb[7] = (short)f2bf(v1.w);
    return bb;
}

// ----------------------- Wfc pad+convert (50 -> 64 rows) -------------------
__global__ __launch_bounds__(256) void wfc_pad(
    const float* __restrict__ Wfc, u16* __restrict__ outp)
{
    int i = blockIdx.x * 256 + threadIdx.x;   // < 16384
    int row = i >> 8, c4 = (i & 255) * 4;
    u16x4 o = { 0, 0, 0, 0 };
    if (row < O_) {
        float4 v = *(const float4*)&Wfc[(size_t)row * 1024 + c4];
        o = u16x4{ f2bf(v.x), f2bf(v.y), f2bf(v.z), f2bf(v.w) };
    }
    *(u16x4*)&outp[(size_t)row * 1024 + c4] = o;
}

// ---------------- bf16 GEMM with fused embed + f32->bf16 -------------------
__global__ __launch_bounds__(256) void gemm_fused(
    const int* __restrict__ x, const float* __restrict__ emb,
    const float* __restrict__ Wih1, const float* __restrict__ b1,
    u16* __restrict__ C)
{
    __shared__ u16 Asm[128][40];
    __shared__ u16 Bsm[128][40];
    const int tid = threadIdx.x, lane = tid & 63, wave = tid >> 6;
    const int wr = wave >> 1, wc = wave & 1;
    const int bm = blockIdx.y, bn = blockIdx.x;
    f32x4 acc[4][4] = {};
    const int r = tid >> 1, kc = (tid & 1) * 16;
    const int grow = bm * 128 + r;
    const int xi = x[grow];
    const float* ag = emb  + (size_t)xi * E_;
    const float* bg = Wih1 + (size_t)(bn * 128 + r) * E_;
    for (int k0 = 0; k0 < E_; k0 += 32) {
        int col = k0 + kc;
        __syncthreads();
        *(bf16x8*)&Asm[r][kc]     = pack8(ag + col);
        *(bf16x8*)&Asm[r][kc + 8] = pack8(ag + col + 8);
        *(bf16x8*)&Bsm[r][kc]     = pack8(bg + col);
        *(bf16x8*)&Bsm[r][kc + 8] = pack8(bg + col + 8);
        __syncthreads();
        bf16x8 af[4], bf[4];
        #pragma unroll
        for (int mt = 0; mt < 4; mt++)
            af[mt] = *(const bf16x8*)&Asm[wr * 64 + mt * 16 + (lane & 15)][(lane >> 4) * 8];
        #pragma unroll
        for (int nt = 0; nt < 4; nt++)
            bf[nt] = *(const bf16x8*)&Bsm[wc * 64 + nt * 16 + (lane & 15)][(lane >> 4) * 8];
        #pragma unroll
        for (int mt = 0; mt < 4; mt++)
            #pragma unroll
            for (int nt = 0; nt < 4; nt++)
                acc[mt][nt] = __builtin_amdgcn_mfma_f32_16x16x32_bf16(
                    af[mt], bf[nt], acc[mt][nt], 0, 0, 0);
    }
    #pragma unroll
    for (int mt = 0; mt < 4; mt++) {
        #pragma unroll
        for (int nt = 0; nt < 4; nt++) {
            int col = bn * 128 + wc * 64 + nt * 16 + (lane & 15);
            float bv = b1[col];
            #pragma unroll
            for (int rr = 0; rr < 4; rr++) {
                int row = bm * 128 + wr * 64 + mt * 16 + (lane >> 4) * 4 + rr;
                C[(size_t)row * G_ + col] = f2bf(acc[mt][nt][rr] + bv);
            }
        }
    }
}

// ------------------------- fused 3-role pipeline ---------------------------
// sents ints: [0..255] sentH1 (grp*32+ug), [256..511] sentXG (bg*32+gg),
// [512..767] prog (bg*32+ug). memset 0 before launch.
__global__ __launch_bounds__(512, 2) void scan12(
    const u16* __restrict__ xgb,     // (B,T,G) bf16  layer-1 gate preacts
    const float* __restrict__ Whh1,
    const float* __restrict__ h01, const float* __restrict__ c01,
    u32* h1pub,                      // (B,T,256) packed 2xbf16
    u32* hx1,                        // (2,B,H) tagged words
    const float* __restrict__ Wih2,  // (G,2H)
    const float* __restrict__ Whh2,
    const float* __restrict__ b2,
    const float* __restrict__ h02, const float* __restrict__ c02,
    u32* ring,                       // (RING,B,1024) packed 2xbf16
    u32* hx2,                        // (2,B,H) tagged words
    u32* h2pk,                       // (B,T,256) packed == u16 (B,T,H)
    int* sents)
{
    __shared__ u16 hl2[2][16][520];     // double-buffered h tile (L1/L2S)
    __shared__ u16 a1cat[16][1032];     // concat h1 tile (G2)
    const int tid = threadIdx.x, lane = tid & 63, wave = tid >> 6;
    const int idx = blockIdx.x;
    const u64 tmask = 0xffff0000ffff0000ull;
    int budget = 1 << 20;
    const int jj = lane & 15, kb = (lane >> 4) * 8;

    if (idx < 64) {
        // ================= role L1: layer-1 scan =================
        const int grp = idx & 7, ug = idx >> 3;
        // zero MFMA pad rows 8..15 of both buffers
        for (int j = tid; j < 2 * 8 * 260; j += 512) {
            int bu = j / (8 * 260), rem = j % (8 * 260);
            int rw = 8 + rem / 260, cl = (rem % 260) * 2;
            *(u32*)&hl2[bu][rw][cl] = 0;
        }
        // Wave owns units [gub, gub+8) x all 4 gates.
        // tile0 cols: j<8 -> gate0(i) unit j; j>=8 -> gate1(f) unit j-8.
        // tile1 cols: j<8 -> gate2(g);        j>=8 -> gate3(o).
        const int gub = ug * 64 + (wave << 3);
        bf16x8 breg0[16], breg1[16];
        {
            const float* w0 = Whh1 + (size_t)((jj >> 3) * H_ + gub + (jj & 7)) * H_ + kb;
            const float* w1 = Whh1 + (size_t)((2 + (jj >> 3)) * H_ + gub + (jj & 7)) * H_ + kb;
            #pragma unroll
            for (int kk = 0; kk < 16; kk++) {
                breg0[kk] = pack8(w0 + kk * 32);
                breg1[kk] = pack8(w1 + kk * 32);
            }
        }
        const bool act = (jj < 8) && ((lane >> 4) < 2);
        const int ucol = gub + jj;          // valid when act
        int brow_[4];
        float cst[4];
        #pragma unroll
        for (int rr = 0; rr < 4; rr++) {
            brow_[rr] = grp * 8 + (lane >> 4) * 4 + rr;
            cst[rr] = act ? c01[brow_[rr] * H_ + ucol] : 0.f;
        }
        #pragma unroll
        for (int j = 0; j < 8; ++j) {       // tagged h0 publish (group slice)
            int k = tid + j * 512;
            int prow = k >> 9, pcol = k & 511;
            ST_AG(hx1 + (size_t)(grp * 8 + prow) * H_ + pcol,
                  (1u << 16) | (u32)f2bf(h01[(grp * 8 + prow) * H_ + pcol]));
        }
        const int crow = tid >> 6, ccol = (tid & 63) * 8;
        int* mysent = sents + grp * 32 + ug;
        __syncthreads();

        #pragma unroll 1
        for (int t = 0; t < T_; ++t) {
            // xg prefetch (independent of h)
            u16 xv[4][4] = {};
            if (act) {
                #pragma unroll
                for (int rr = 0; rr < 4; rr++) {
                    const size_t xb = ((size_t)brow_[rr] * T_ + t) * G_ + ucol;
                    xv[rr][0] = xgb[xb];        xv[rr][1] = xgb[xb + 512];
                    xv[rr][2] = xgb[xb + 1024]; xv[rr][3] = xgb[xb + 1536];
                }
            }
            // tagged self-poll of h_t -> stage hl2[t&1]
            u64* src = (u64*)(hx1 + (size_t)(t & 1) * (B_ * H_)
                              + (size_t)(grp * 8 + crow) * H_ + ccol);
            const u32 wt = (u32)(t + 1);
            const u64 want = ((u64)wt << 16) | ((u64)wt << 48);
            u64 v0 = LD_AG(src + 0), v1 = LD_AG(src + 1);
            u64 v2 = LD_AG(src + 2), v3 = LD_AG(src + 3);
            int spin = 0;
            while ((((v0 ^ want) | (v1 ^ want) | (v2 ^ want) | (v3 ^ want)) & tmask) != 0) {
                if (--budget < 0) break;
                if (++spin > 2) __builtin_amdgcn_s_sleep(1);
                if ((v0 ^ want) & tmask) v0 = LD_AG(src + 0);
                if ((v1 ^ want) & tmask) v1 = LD_AG(src + 1);
                if ((v2 ^ want) & tmask) v2 = LD_AG(src + 2);
                if ((v3 ^ want) & tmask) v3 = LD_AG(src + 3);
            }
            u32x4 pk = { (u32)(v0 & 0xffff) | ((u32)(v0 >> 32) << 16),
                         (u32)(v1 & 0xffff) | ((u32)(v1 >> 32) << 16),
                         (u32)(v2 & 0xffff) | ((u32)(v2 >> 32) << 16),
                         (u32)(v3 & 0xffff) | ((u32)(v3 >> 32) << 16) };
            *(u32x4*)&hl2[t & 1][crow][ccol] = pk;
            __syncthreads();   // the ONLY barrier this step

            f32x4 a0 = {0,0,0,0}, a1 = {0,0,0,0}, a2 = {0,0,0,0}, a3 = {0,0,0,0};
            #pragma unroll
            for (int kk = 0; kk < 16; kk += 2) {
                bf16x8 f0 = *(const bf16x8*)&hl2[t & 1][jj][kb + kk * 32];
                bf16x8 f1 = *(const bf16x8*)&hl2[t & 1][jj][kb + (kk + 1) * 32];
                a0 = __builtin_amdgcn_mfma_f32_16x16x32_bf16(f0, breg0[kk],     a0, 0, 0, 0);
                a1 = __builtin_amdgcn_mfma_f32_16x16x32_bf16(f1, breg0[kk + 1], a1, 0, 0, 0);
                a2 = __builtin_amdgcn_mfma_f32_16x16x32_bf16(f0, breg1[kk],     a2, 0, 0, 0);
                a3 = __builtin_amdgcn_mfma_f32_16x16x32_bf16(f1, breg1[kk + 1], a3, 0, 0, 0);
            }
            // intra-wave gate exchange + cell update (active lanes own
            // (4 rows x 1 unit); partners j^8 provide f and o)
            #pragma unroll
            for (int rr = 0; rr < 4; rr++) {
                float ti = a0[rr] + a1[rr];          // tile0: i (j<8) / f (j>=8)
                float tg = a2[rr] + a3[rr];          // tile1: g / o
                float fo = __shfl_xor(ti, 8);
                float oo = __shfl_xor(tg, 8);
                float ip = ti + bf2f(xv[rr][0]);
                float fp = fo + bf2f(xv[rr][1]);
                float gp = tg + bf2f(xv[rr][2]);
                float op = oo + bf2f(xv[rr][3]);
                float gi = sigm(ip), gf = sigm(fp), gc = tanh_f(gp), go = sigm(op);
                cst[rr] = gf * cst[rr] + gi * gc;
                float h = go * tanh_f(cst[rr]);
                u32 me = f2bf(h);
                u32 ot = (u32)__shfl_xor((int)me, 1);
                if (act) {
                    ST_AG(hx1 + (size_t)((t + 1) & 1) * (B_ * H_)
                          + (size_t)brow_[rr] * H_ + ucol,
                          ((u32)(t + 2) << 16) | me);
                    if (!(jj & 1))
                        ST_AG(h1pub + ((size_t)brow_[rr] * T_ + t) * 256 + (ucol >> 1),
                              me | (ot << 16));
                }
            }
            if (tid == 0) ST_AG(mysent, t + 1);   // "issued"; consumer waits t+2
        }
        __syncthreads();                          // drain last step's stores
        if (tid == 0) ST_AG(mysent, T_ + 1);      // 257: final visibility

    } else if (idx < 192) {
        // ========== role G2: layer-2 input projection (R13 verbatim) ==========
        const int bg = idx & 7, gg = (idx - 64) >> 3;    // gg in 0..15
        for (int j = tid; j < 8 * 516; j += 512) {
            int rw = 8 + j / 516, cl = (j % 516) * 2;
            *(u32*)&a1cat[rw][cl] = 0;
        }
        const int gcol = gg * 128 + wave * 16 + (lane & 15);
        bf16x8 bi[32];
        {
            const float* wr0 = Wih2 + (size_t)gcol * 1024 + ((lane >> 4) * 8);
            #pragma unroll
            for (int kk = 0; kk < 32; kk++) bi[kk] = pack8(wr0 + kk * 32);
        }
        const float bias = b2[gcol];
        const int crow = tid >> 6, ccol = (tid & 63) * 16;
        const int myb  = bg * 8 + crow;
        const int myfb = (7 - bg) * 8 + (7 - crow);
        const u32* __restrict__ hbase =
            h1pub + (size_t)((ccol < 512) ? myb : myfb) * T_ * 256;
        const int  cadj  = (ccol < 512) ? (ccol >> 1) : ((ccol - 512) >> 1);
        __syncthreads();

        #pragma unroll 1
        for (int t = 0; t < T_; ++t) {
            if (tid < 16) {
                int g2 = (tid < 8) ? bg : (7 - bg);
                int* sp = sents + g2 * 32 + (tid & 7);
                const int want = t + 2;
                int spin = 0;
                while (LD_AG(sp) < want) {
                    if (--budget < 0) break;
                    if (++spin > 2) __builtin_amdgcn_s_sleep(2);
                }
            } else if (tid < 24 && t >= RING) {
                int* sp = sents + 512 + bg * 32 + (tid - 16);
                const int want = t - (RING - 1);
                int spin = 0;
                while (LD_AG(sp) < want) {
                    if (--budget < 0) break;
                    if (++spin > 2) __builtin_amdgcn_s_sleep(2);
                }
            }
            __syncthreads();

            const u32* s0 = hbase + (size_t)t * 256 + cadj;
            u32x4 q0 = *(const u32x4*)(s0);
            u32x4 q1 = *(const u32x4*)(s0 + 4);
            *(u32x4*)&a1cat[crow][ccol]     = q0;
            *(u32x4*)&a1cat[crow][ccol + 8] = q1;
            __syncthreads();

            f32x4 a0 = {0,0,0,0}, a1 = {0,0,0,0}, a2 = {0,0,0,0}, a3 = {0,0,0,0};
            const int ar = lane & 15, ac = (lane >> 4) * 8;
            #pragma unroll
            for (int kk = 0; kk < 32; kk += 4) {
                bf16x8 f0 = *(const bf16x8*)&a1cat[ar][ac + kk * 32];
                bf16x8 f1 = *(const bf16x8*)&a1cat[ar][ac + (kk + 1) * 32];
                bf16x8 f2 = *(const bf16x8*)&a1cat[ar][ac + (kk + 2) * 32];
                bf16x8 f3 = *(const bf16x8*)&a1cat[ar][ac + (kk + 3) * 32];
                a0 = __builtin_amdgcn_mfma_f32_16x16x32_bf16(f0, bi[kk],     a0, 0, 0, 0);
                a1 = __builtin_amdgcn_mfma_f32_16x16x32_bf16(f1, bi[kk + 1], a1, 0, 0, 0);
                a2 = __builtin_amdgcn_mfma_f32_16x16x32_bf16(f2, bi[kk + 2], a2, 0, 0, 0);
                a3 = __builtin_amdgcn_mfma_f32_16x16x32_bf16(f3, bi[kk + 3], a3, 0, 0, 0);
            }
            #pragma unroll
            for (int rr = 0; rr < 4; rr++) {
                int br = (lane >> 4) * 4 + rr;
                u32 me = f2bf((a0[rr] + a1[rr]) + (a2[rr] + a3[rr]) + bias);
                u32 ot = (u32)__shfl_xor((int)me, 1);
                if (br < 8 && !(lane & 1))
                    ST_AG(ring + ((size_t)(t & (RING - 1)) * B_ + bg * 8 + br) * 1024
                          + (gcol >> 1), me | (ot << 16));
            }
            __syncthreads();   // drain ring stores + protect a1cat
            if (tid == 0) ST_AG(sents + 256 + bg * 32 + gg, t + 1);
        }

    } else {
        // ================= role L2S: layer-2 scan (single-barrier) ===========
        const int bg = idx & 7, ug = (idx - 192) >> 3;
        for (int j = tid; j < 2 * 8 * 260; j += 512) {
            int bu = j / (8 * 260), rem = j % (8 * 260);
            int rw = 8 + rem / 260, cl = (rem % 260) * 2;
            *(u32*)&hl2[bu][rw][cl] = 0;
        }
        const int gub = ug * 64 + (wave << 3);
        bf16x8 breg0[16], breg1[16];
        {
            const float* w0 = Whh2 + (size_t)((jj >> 3) * H_ + gub + (jj & 7)) * H_ + kb;
            const float* w1 = Whh2 + (size_t)((2 + (jj >> 3)) * H_ + gub + (jj & 7)) * H_ + kb;
            #pragma unroll
            for (int kk = 0; kk < 16; kk++) {
                breg0[kk] = pack8(w0 + kk * 32);
                breg1[kk] = pack8(w1 + kk * 32);
            }
        }
        const bool act = (jj < 8) && ((lane >> 4) < 2);
        const int ucol = gub + jj;
        int brow_[4];
        float cst[4];
        #pragma unroll
        for (int rr = 0; rr < 4; rr++) {
            brow_[rr] = bg * 8 + (lane >> 4) * 4 + rr;
            cst[rr] = act ? c02[brow_[rr] * H_ + ucol] : 0.f;
        }
        #pragma unroll
        for (int j = 0; j < 8; ++j) {       // tagged h0 publish
            int k = tid + j * 512;
            int prow = k >> 9, pcol = k & 511;
            ST_AG(hx2 + (size_t)(bg * 8 + prow) * H_ + pcol,
                  (1u << 16) | (u32)f2bf(h02[(bg * 8 + prow) * H_ + pcol]));
        }
        const int crow = tid >> 6, ccol = (tid & 63) * 8;
        const int sh = (ucol & 1) * 16;
        __syncthreads();

        #pragma unroll 1
        for (int t = 0; t < T_; ++t) {
            // ring sentinel poll (16 scalars) — gates this step's ring loads
            if (tid < 16) {
                int* sp = sents + 256 + bg * 32 + tid;
                const int want = t + 1;
                int spin = 0;
                while (LD_AG(sp) < want) {
                    if (--budget < 0) break;
                    if (++spin > 2) __builtin_amdgcn_s_sleep(2);
                }
            }
            // tagged self-poll of h2[t] -> stage hl2[t&1]
            u64* src = (u64*)(hx2 + (size_t)(t & 1) * (B_ * H_)
                              + (size_t)(bg * 8 + crow) * H_ + ccol);
            const u32 wt = (u32)(t + 1);
            const u64 want = ((u64)wt << 16) | ((u64)wt << 48);
            u64 v0 = LD_AG(src + 0), v1 = LD_AG(src + 1);
            u64 v2 = LD_AG(src + 2), v3 = LD_AG(src + 3);
            int spin = 0;
            while ((((v0 ^ want) | (v1 ^ want) | (v2 ^ want) | (v3 ^ want)) & tmask) != 0) {
                if (--budget < 0) break;
                if (++spin > 2) __builtin_amdgcn_s_sleep(1);
                if ((v0 ^ want) & tmask) v0 = LD_AG(src + 0);
                if ((v1 ^ want) & tmask) v1 = LD_AG(src + 1);
                if ((v2 ^ want) & tmask) v2 = LD_AG(src + 2);
                if ((v3 ^ want) & tmask) v3 = LD_AG(src + 3);
            }
            u32x4 pk = { (u32)(v0 & 0xffff) | ((u32)(v0 >> 32) << 16),
                         (u32)(v1 & 0xffff) | ((u32)(v1 >> 32) << 16),
                         (u32)(v2 & 0xffff) | ((u32)(v2 >> 32) << 16),
                         (u32)(v3 & 0xffff) | ((u32)(v3 >> 32) << 16) };
            *(u32x4*)&hl2[t & 1][crow][ccol] = pk;
            __syncthreads();   // the ONLY barrier: LDS ready + sentinel seen

            // prog delayed one step: barrier(t) drained step t-1 ring reads
            if (tid == 0 && t > 0) ST_AG(sents + 512 + bg * 32 + ug, t);

            // ring loads (sentinel-confirmed); consumed by same thread below
            u32 xw[4][4] = {};
            if (act) {
                const size_t sb = (size_t)(t & (RING - 1)) * (B_ * 1024);
                #pragma unroll
                for (int rr = 0; rr < 4; rr++) {
                    const size_t rb = sb + (size_t)brow_[rr] * 1024 + (ucol >> 1);
                    xw[rr][0] = LD_AG(ring + rb);
                    xw[rr][1] = LD_AG(ring + rb + 256);
                    xw[rr][2] = LD_AG(ring + rb + 512);
                    xw[rr][3] = LD_AG(ring + rb + 768);
                }
            }

            f32x4 a0 = {0,0,0,0}, a1 = {0,0,0,0}, a2 = {0,0,0,0}, a3 = {0,0,0,0};
            #pragma unroll
            for (int kk = 0; kk < 16; kk += 2) {
                bf16x8 f0 = *(const bf16x8*)&hl2[t & 1][jj][kb + kk * 32];
                bf16x8 f1 = *(const bf16x8*)&hl2[t & 1][jj][kb + (kk + 1) * 32];
                a0 = __builtin_amdgcn_mfma_f32_16x16x32_bf16(f0, breg0[kk],     a0, 0, 0, 0);
                a1 = __builtin_amdgcn_mfma_f32_16x16x32_bf16(f1, breg0[kk + 1], a1, 0, 0, 0);
                a2 = __builtin_amdgcn_mfma_f32_16x16x32_bf16(f0, breg1[kk],     a2, 0, 0, 0);
                a3 = __builtin_amdgcn_mfma_f32_16x16x32_bf16(f1, breg1[kk + 1], a3, 0, 0, 0);
            }
            #pragma unroll
            for (int rr = 0; rr < 4; rr++) {
                float ti = a0[rr] + a1[rr];
                float tg = a2[rr] + a3[rr];
                float fo = __shfl_xor(ti, 8);
                float oo = __shfl_xor(tg, 8);
                float ip = ti + bf2f((u16)(xw[rr][0] >> sh));
                float fp = fo + bf2f((u16)(xw[rr][1] >> sh));
                float gp = tg + bf2f((u16)(xw[rr][2] >> sh));
                float op = oo + bf2f((u16)(xw[rr][3] >> sh));
                float gi = sigm(ip), gf = sigm(fp), gc = tanh_f(gp), go = sigm(op);
                cst[rr] = gf * cst[rr] + gi * gc;
                float h = go * tanh_f(cst[rr]);
                u32 me = f2bf(h);
                u32 ot = (u32)__shfl_xor((int)me, 1);
                if (act) {
                    ST_AG(hx2 + (size_t)((t + 1) & 1) * (B_ * H_)
                          + (size_t)brow_[rr] * H_ + ucol,
                          ((u32)(t + 2) << 16) | me);
                    if (!(jj & 1))
                        h2pk[((size_t)brow_[rr] * T_ + t) * 256 + (ucol >> 1)]
                            = me | (ot << 16);
                }
            }
        }
    }
}

// --------------------------- FC (MFMA) + log_softmax -----------------------
__global__ __launch_bounds__(256) void fc_mfma(
    const u16* __restrict__ h2, const u16* __restrict__ Wfcp,   // (64,1024)
    const float* __restrict__ bfc, float* __restrict__ out)
{
    __shared__ u16 hl[16][1032];
    __shared__ float cl[16][68];
    const int tid = threadIdx.x, lane = tid & 63, wave = tid >> 6;
    const int r0 = blockIdx.x * 16;
    const int b = r0 >> 8;
    const int fr0 = (63 - b) * T_ + (r0 & 255);
    #pragma unroll
    for (int j = 0; j < 16; ++j) {
        int k = tid + j * 256;
        int row = k >> 8, c4 = k & 255;
        const u16* src = (c4 < 128)
            ? h2 + (size_t)(r0 + row) * H_ + c4 * 4
            : h2 + (size_t)(fr0 + row) * H_ + (c4 - 128) * 4;
        *(u64*)&hl[row][c4 * 4] = *(const u64*)src;
    }
    __syncthreads();
    const int ar = lane & 15, ac = (lane >> 4) * 8;
    const u16* wrow = Wfcp + (size_t)(wave * 16 + ar) * 1024 + ac;
    f32x4 a0 = {0,0,0,0}, a1 = {0,0,0,0};
    #pragma unroll
    for (int kk = 0; kk < 32; kk += 2) {
        bf16x8 f0 = *(const bf16x8*)&hl[ar][ac + kk * 32];
        bf16x8 f1 = *(const bf16x8*)&hl[ar][ac + (kk + 1) * 32];
        bf16x8 w0 = *(const bf16x8*)(wrow + kk * 32);
        bf16x8 w1 = *(const bf16x8*)(wrow + (kk + 1) * 32);
        a0 = __builtin_amdgcn_mfma_f32_16x16x32_bf16(f0, w0, a0, 0, 0, 0);
        a1 = __builtin_amdgcn_mfma_f32_16x16x32_bf16(f1, w1, a1, 0, 0, 0);
    }
    #pragma unroll
    for (int rr = 0; rr < 4; rr++)
        cl[(lane >> 4) * 4 + rr][wave * 16 + ar] = a0[rr] + a1[rr];
    __syncthreads();
    #pragma unroll
    for (int rr2 = 0; rr2 < 4; rr2++) {
        int row = wave * 4 + rr2;
        float acc = (lane < O_) ? cl[row][lane] + bfc[lane] : -1e30f;
        float m = acc;
        #pragma unroll
        for (int off = 32; off > 0; off >>= 1) m = fmaxf(m, __shfl_xor(m, off));
        float e = (lane < O_) ? __expf(acc - m) : 0.f;
        float sm = e;
        #pragma unroll
        for (int off = 32; off > 0; off >>= 1) sm += __shfl_xor(sm, off);
        float lse = m + __logf(sm);
        if (lane < O_) out[(size_t)(r0 + row) * O_ + lane] = acc - lse;
    }
}

// ------------------------------ launcher -----------------------------------

extern "C" void kernel_launch(void* const* d_in, const int* in_sizes, int n_in,
                              void* d_out, int out_size, void* d_ws, size_t ws_size,
                              hipStream_t stream)
{
    (void)in_sizes; (void)n_in; (void)out_size;
    const int*   x    = (const int*)  d_in[0];
    const float* emb  = (const float*)d_in[1];
    const float* Wih1 = (const float*)d_in[2];
    const float* Whh1 = (const float*)d_in[3];
    const float* b1   = (const float*)d_in[4];
    const float* h01  = (const float*)d_in[5];
    const float* c01  = (const float*)d_in[6];
    const float* Wih2 = (const float*)d_in[7];
    const float* Whh2 = (const float*)d_in[8];
    const float* b2   = (const float*)d_in[9];
    const float* h02  = (const float*)d_in[10];
    const float* c02  = (const float*)d_in[11];
    const float* Wfc  = (const float*)d_in[12];
    const float* bfc  = (const float*)d_in[13];
    float* out = (float*)d_out;

    char* ws = (char*)d_ws;
    size_t off = 0;
    auto alloc = [&](size_t bytes) {
        char* p = ws + off; off += (bytes + 255) & ~(size_t)255; return p;
    };
    u16* Wfcp  = (u16*)alloc((size_t)64 * 1024 * 2);          //   0.13 MB
    u16* xgb   = (u16*)alloc((size_t)NROW * G_ * 2);          //  67.11 MB
    u32* h1pub = (u32*)alloc((size_t)NROW * 256 * 4);         //  16.78 MB
    u32* ring  = (u32*)alloc((size_t)RING * B_ * 1024 * 4);   //   4.19 MB
    u32* hx1   = (u32*)alloc((size_t)2 * B_ * H_ * 4);        //   0.26 MB
    u32* hx2   = (u32*)alloc((size_t)2 * B_ * H_ * 4);        //   0.26 MB
    u32* h2pk  = (u32*)alloc((size_t)NROW * 256 * 4);         //  16.78 MB
    int* sents = (int*)alloc(768 * sizeof(int));              //   3 KB
    if (off > ws_size) return;   // clean diagnostic failure, never OOB

    hipMemsetAsync(sents, 0, 768 * sizeof(int), stream);
    wfc_pad<<<64, 256, 0, stream>>>(Wfc, Wfcp);

    gemm_fused<<<dim3(G_ / 128, NROW / 128), 256, 0, stream>>>(
        x, emb, Wih1, b1, xgb);

    scan12<<<256, 512, 0, stream>>>(xgb, Whh1, h01, c01, h1pub, hx1,
                                    Wih2, Whh2, b2, h02, c02, ring, hx2, h2pk,
                                    sents);

    fc_mfma<<<NROW / 16, 256, 0, stream>>>((const u16*)h2pk, Wfcp, bfc, out);
}

// Round 15
// 877.533 us; speedup vs baseline: 1.6874x; 1.6874x over previous
//
#include <hip/hip_runtime.h>

// ---------------------------------------------------------------------------
// BiLSTM tagger: emb -> [fwd LSTM, batch-flipped copy] x2 -> FC -> log_softmax
// B=64, T=256, V=50000, E=256, H=512, O=50. Gate dim G=4H=2048.
//
// R15 = R13 verbatim (best verified: 879 us, absmax 0.015625).
//   pre: gemm_fused (A = emb[x[row]], B = Wih1, both converted in staging)
//   scan12 (256 wgs = 1/CU, XCD-grouped by blockIdx&7):
//     L1  (0..63):   layer-1 scan; tagged hx1 self-poll; reads xgb.
//     G2  (64..191): layer-2 input projection (sentinel-gated plain loads).
//     L2S (192..255): layer-2 scan; writes packed h2.
//   post: fc_mfma (Wfc padded 50->64 by wfc_pad).
// R14's single-barrier wave layout REVERTED: it serialized the elementwise
// phase into 16/64 lanes (+72% scan time). Lane-parallel elementwise + two
// barriers is the winning tradeoff in this latency-bound regime.
// ---------------------------------------------------------------------------

#define B_ 64
#define T_ 256
#define E_ 256
#define H_ 512
#define G_ 2048
#define O_ 50
#define NROW (B_ * T_)   // 16384
#define RING 16

typedef unsigned short u16;
typedef unsigned int u32;
typedef unsigned long long u64;
typedef short bf16x8 __attribute__((ext_vector_type(8)));
typedef u16 u16x4 __attribute__((ext_vector_type(4)));
typedef u32 u32x4 __attribute__((ext_vector_type(4)));
typedef float f32x4 __attribute__((ext_vector_type(4)));

#define LD_AG(p)    __hip_atomic_load((p), __ATOMIC_RELAXED, __HIP_MEMORY_SCOPE_AGENT)
#define ST_AG(p, v) __hip_atomic_store((p), (v), __ATOMIC_RELAXED, __HIP_MEMORY_SCOPE_AGENT)

__device__ __forceinline__ u16 f2bf(float f) {
    unsigned u = __float_as_uint(f);
    return (u16)((u + 0x7fffu + ((u >> 16) & 1u)) >> 16);
}
__device__ __forceinline__ float bf2f(u16 x) {
    return __uint_as_float(((u32)x) << 16);
}
__device__ __forceinline__ float sigm(float x) {
    x = fminf(fmaxf(x, -30.f), 30.f);
    return 1.f / (1.f + __expf(-x));
}
__device__ __forceinline__ float tanh_f(float x) {
    x = fminf(fmaxf(x, -15.f), 15.f);
    float e = __expf(2.f * x);
    return (e - 1.f) / (e + 1.f);
}
__device__ __forceinline__ bf16x8 pack8(const float* p) {
    float4 v0 = *(const float4*)p;
    float4 v1 = *(const float4*)(p + 4);
    bf16x8 bb;
    bb[0] = (short)f2bf(v0.x); bb[1] = (short)f2bf(v0.y);
    bb[2] = (short)f2bf(v0.z); bb[3] = (short)f2bf(v0.w);
    bb[4] = (short)f2bf(v1.x); bb[5] = (short)f2bf(v1.y);
    bb[6] = (short)f2bf(v1.z); bb[7] = (short)f2bf(v1.w);
    return bb;
}

// ----------------------- Wfc pad+convert (50 -> 64 rows) -------------------
__global__ __launch_bounds__(256) void wfc_pad(
    const float* __restrict__ Wfc, u16* __restrict__ outp)
{
    int i = blockIdx.x * 256 + threadIdx.x;   // < 16384
    int row = i >> 8, c4 = (i & 255) * 4;
    u16x4 o = { 0, 0, 0, 0 };
    if (row < O_) {
        float4 v = *(const float4*)&Wfc[(size_t)row * 1024 + c4];
        o = u16x4{ f2bf(v.x), f2bf(v.y), f2bf(v.z), f2bf(v.w) };
    }
    *(u16x4*)&outp[(size_t)row * 1024 + c4] = o;
}

// ---------------- bf16 GEMM with fused embed + f32->bf16 -------------------
// xgb[row][col] = emb[x[row]] . Wih1[col] + b1[col]; row = b*T+t, col in G.
__global__ __launch_bounds__(256) void gemm_fused(
    const int* __restrict__ x, const float* __restrict__ emb,
    const float* __restrict__ Wih1, const float* __restrict__ b1,
    u16* __restrict__ C)
{
    __shared__ u16 Asm[128][40];
    __shared__ u16 Bsm[128][40];
    const int tid = threadIdx.x, lane = tid & 63, wave = tid >> 6;
    const int wr = wave >> 1, wc = wave & 1;
    const int bm = blockIdx.y, bn = blockIdx.x;
    f32x4 acc[4][4] = {};
    const int r = tid >> 1, kc = (tid & 1) * 16;
    const int grow = bm * 128 + r;
    const int xi = x[grow];
    const float* ag = emb  + (size_t)xi * E_;
    const float* bg = Wih1 + (size_t)(bn * 128 + r) * E_;
    for (int k0 = 0; k0 < E_; k0 += 32) {
        int col = k0 + kc;
        __syncthreads();
        *(bf16x8*)&Asm[r][kc]     = pack8(ag + col);
        *(bf16x8*)&Asm[r][kc + 8] = pack8(ag + col + 8);
        *(bf16x8*)&Bsm[r][kc]     = pack8(bg + col);
        *(bf16x8*)&Bsm[r][kc + 8] = pack8(bg + col + 8);
        __syncthreads();
        bf16x8 af[4], bf[4];
        #pragma unroll
        for (int mt = 0; mt < 4; mt++)
            af[mt] = *(const bf16x8*)&Asm[wr * 64 + mt * 16 + (lane & 15)][(lane >> 4) * 8];
        #pragma unroll
        for (int nt = 0; nt < 4; nt++)
            bf[nt] = *(const bf16x8*)&Bsm[wc * 64 + nt * 16 + (lane & 15)][(lane >> 4) * 8];
        #pragma unroll
        for (int mt = 0; mt < 4; mt++)
            #pragma unroll
            for (int nt = 0; nt < 4; nt++)
                acc[mt][nt] = __builtin_amdgcn_mfma_f32_16x16x32_bf16(
                    af[mt], bf[nt], acc[mt][nt], 0, 0, 0);
    }
    #pragma unroll
    for (int mt = 0; mt < 4; mt++) {
        #pragma unroll
        for (int nt = 0; nt < 4; nt++) {
            int col = bn * 128 + wc * 64 + nt * 16 + (lane & 15);
            float bv = b1[col];
            #pragma unroll
            for (int rr = 0; rr < 4; rr++) {
                int row = bm * 128 + wr * 64 + mt * 16 + (lane >> 4) * 4 + rr;
                C[(size_t)row * G_ + col] = f2bf(acc[mt][nt][rr] + bv);
            }
        }
    }
}

// ------------------------- fused 3-role pipeline ---------------------------
// sents ints: [0..255] sentH1 (grp*32+ug), [256..511] sentXG (bg*32+gg),
// [512..767] prog (bg*32+ug). memset 0 before launch.
__global__ __launch_bounds__(512, 2) void scan12(
    const u16* __restrict__ xgb,     // (B,T,G) bf16  layer-1 gate preacts
    const float* __restrict__ Whh1,
    const float* __restrict__ h01, const float* __restrict__ c01,
    u32* h1pub,                      // (B,T,256) packed 2xbf16
    u32* hx1,                        // (2,B,H) tagged words
    const float* __restrict__ Wih2,  // (G,2H)
    const float* __restrict__ Whh2,
    const float* __restrict__ b2,
    const float* __restrict__ h02, const float* __restrict__ c02,
    u32* ring,                       // (RING,B,1024) packed 2xbf16
    u32* hx2,                        // (2,B,H) tagged words
    u32* h2pk,                       // (B,T,256) packed == u16 (B,T,H)
    int* sents)
{
    __shared__ u16 hl[16][520];
    __shared__ u16 a1cat[16][1032];
    __shared__ float glds[4][8][68];
    const int tid = threadIdx.x, lane = tid & 63, wave = tid >> 6;
    const int idx = blockIdx.x;
    const u64 tmask = 0xffff0000ffff0000ull;
    int budget = 1 << 20;

    if (idx < 64) {
        // ================= role L1: layer-1 scan =================
        const int grp = idx & 7, ug = idx >> 3;
        const int gw = wave >> 1, uh = wave & 1;
        for (int j = tid; j < 8 * 260; j += 512) {
            int rw = 8 + j / 260, cl = (j % 260) * 2;
            *(u32*)&hl[rw][cl] = 0;
        }
        bf16x8 breg0[16], breg1[16];
        #pragma unroll
        for (int tt = 0; tt < 2; tt++) {
            const float* wr0 = Whh1
                + (size_t)(gw * H_ + ug * 64 + uh * 32 + tt * 16 + (lane & 15)) * H_
                + ((lane >> 4) * 8);
            #pragma unroll
            for (int kk = 0; kk < 16; kk++) {
                bf16x8 bb = pack8(wr0 + kk * 32);
                if (tt == 0) breg0[kk] = bb; else breg1[kk] = bb;
            }
        }
        const int bb_ = tid >> 6, uu = tid & 63;
        const int brow = grp * 8 + bb_, ucol = ug * 64 + uu;
        float c = c01[brow * H_ + ucol];
        #pragma unroll
        for (int j = 0; j < 8; ++j) {                    // tagged h0 publish
            int k = tid + j * 512;
            int prow = k >> 9, pcol = k & 511;
            ST_AG(hx1 + (size_t)(grp * 8 + prow) * H_ + pcol,
                  (1u << 16) | (u32)f2bf(h01[(grp * 8 + prow) * H_ + pcol]));
        }
        const int crow = tid >> 6, ccol = (tid & 63) * 8;
        int* mysent = sents + grp * 32 + ug;
        __syncthreads();

        #pragma unroll 1
        for (int t = 0; t < T_; ++t) {
            const size_t xb = ((size_t)brow * T_ + t) * G_ + ucol;
            u16 xi = xgb[xb], xf = xgb[xb + 512];
            u16 xgg = xgb[xb + 1024], xo = xgb[xb + 1536];

            u64* src = (u64*)(hx1 + (size_t)(t & 1) * (B_ * H_)
                              + (size_t)(grp * 8 + crow) * H_ + ccol);
            const u32 wt = (u32)(t + 1);
            const u64 want = ((u64)wt << 16) | ((u64)wt << 48);
            u64 v0 = LD_AG(src + 0), v1 = LD_AG(src + 1);
            u64 v2 = LD_AG(src + 2), v3 = LD_AG(src + 3);
            int spin = 0;
            while ((((v0 ^ want) | (v1 ^ want) | (v2 ^ want) | (v3 ^ want)) & tmask) != 0) {
                if (--budget < 0) break;
                if (++spin > 2) __builtin_amdgcn_s_sleep(1);
                if ((v0 ^ want) & tmask) v0 = LD_AG(src + 0);
                if ((v1 ^ want) & tmask) v1 = LD_AG(src + 1);
                if ((v2 ^ want) & tmask) v2 = LD_AG(src + 2);
                if ((v3 ^ want) & tmask) v3 = LD_AG(src + 3);
            }
            u32x4 pk = { (u32)(v0 & 0xffff) | ((u32)(v0 >> 32) << 16),
                         (u32)(v1 & 0xffff) | ((u32)(v1 >> 32) << 16),
                         (u32)(v2 & 0xffff) | ((u32)(v2 >> 32) << 16),
                         (u32)(v3 & 0xffff) | ((u32)(v3 >> 32) << 16) };
            *(u32x4*)&hl[crow][ccol] = pk;
            __syncthreads();

            f32x4 a0 = {0,0,0,0}, a1 = {0,0,0,0}, a2 = {0,0,0,0}, a3 = {0,0,0,0};
            const int ar = lane & 15, ac = (lane >> 4) * 8;
            #pragma unroll
            for (int kk = 0; kk < 16; kk += 2) {
                bf16x8 f0 = *(const bf16x8*)&hl[ar][ac + kk * 32];
                bf16x8 f1 = *(const bf16x8*)&hl[ar][ac + (kk + 1) * 32];
                a0 = __builtin_amdgcn_mfma_f32_16x16x32_bf16(f0, breg0[kk],     a0, 0, 0, 0);
                a1 = __builtin_amdgcn_mfma_f32_16x16x32_bf16(f1, breg0[kk + 1], a1, 0, 0, 0);
                a2 = __builtin_amdgcn_mfma_f32_16x16x32_bf16(f0, breg1[kk],     a2, 0, 0, 0);
                a3 = __builtin_amdgcn_mfma_f32_16x16x32_bf16(f1, breg1[kk + 1], a3, 0, 0, 0);
            }
            #pragma unroll
            for (int rr = 0; rr < 4; rr++) {
                int br = (lane >> 4) * 4 + rr;
                if (br < 8) {
                    glds[gw][br][uh * 32 + (lane & 15)]      = a0[rr] + a1[rr];
                    glds[gw][br][uh * 32 + 16 + (lane & 15)] = a2[rr] + a3[rr];
                }
            }
            __syncthreads();

            float ip = glds[0][bb_][uu] + bf2f(xi);
            float fp = glds[1][bb_][uu] + bf2f(xf);
            float gp = glds[2][bb_][uu] + bf2f(xgg);
            float op = glds[3][bb_][uu] + bf2f(xo);
            float gi = sigm(ip), gf = sigm(fp), gc = tanh_f(gp), go = sigm(op);
            c = gf * c + gi * gc;
            float h = go * tanh_f(c);
            u32 me = f2bf(h);
            ST_AG(hx1 + (size_t)((t + 1) & 1) * (B_ * H_) + (size_t)brow * H_ + ucol,
                  ((u32)(t + 2) << 16) | me);
            u32 ot = (u32)__shfl_xor((int)me, 1);
            if (!(uu & 1))
                ST_AG(h1pub + ((size_t)brow * T_ + t) * 256 + (ucol >> 1),
                      me | (ot << 16));
            if (tid == 0) ST_AG(mysent, t + 1);   // "issued" semantics
        }
        __syncthreads();                          // drain last step's stores
        if (tid == 0) ST_AG(mysent, T_ + 1);      // 257: final visibility

    } else if (idx < 192) {
        // ================= role G2: layer-2 input projection =================
        const int bg = idx & 7, gg = (idx - 64) >> 3;    // gg in 0..15
        for (int j = tid; j < 8 * 516; j += 512) {
            int rw = 8 + j / 516, cl = (j % 516) * 2;
            *(u32*)&a1cat[rw][cl] = 0;
        }
        const int gcol = gg * 128 + wave * 16 + (lane & 15);
        bf16x8 bi[32];
        {
            const float* wr0 = Wih2 + (size_t)gcol * 1024 + ((lane >> 4) * 8);
            #pragma unroll
            for (int kk = 0; kk < 32; kk++) bi[kk] = pack8(wr0 + kk * 32);
        }
        const float bias = b2[gcol];
        const int crow = tid >> 6, ccol = (tid & 63) * 16;
        const int myb  = bg * 8 + crow;
        const int myfb = (7 - bg) * 8 + (7 - crow);
        // PLAIN loads value-safe on h1pub (write-once, replay-deterministic).
        const u32* __restrict__ hbase =
            h1pub + (size_t)((ccol < 512) ? myb : myfb) * T_ * 256;
        const int  cadj  = (ccol < 512) ? (ccol >> 1) : ((ccol - 512) >> 1);
        __syncthreads();

        #pragma unroll 1
        for (int t = 0; t < T_; ++t) {
            if (tid < 16) {
                int g2 = (tid < 8) ? bg : (7 - bg);
                int* sp = sents + g2 * 32 + (tid & 7);
                const int want = t + 2;
                int spin = 0;
                while (LD_AG(sp) < want) {
                    if (--budget < 0) break;
                    if (++spin > 2) __builtin_amdgcn_s_sleep(2);
                }
            } else if (tid < 24 && t >= RING) {
                int* sp = sents + 512 + bg * 32 + (tid - 16);
                const int want = t - (RING - 1);
                int spin = 0;
                while (LD_AG(sp) < want) {
                    if (--budget < 0) break;
                    if (++spin > 2) __builtin_amdgcn_s_sleep(2);
                }
            }
            __syncthreads();

            const u32* s0 = hbase + (size_t)t * 256 + cadj;
            u32x4 q0 = *(const u32x4*)(s0);
            u32x4 q1 = *(const u32x4*)(s0 + 4);
            *(u32x4*)&a1cat[crow][ccol]     = q0;
            *(u32x4*)&a1cat[crow][ccol + 8] = q1;
            __syncthreads();

            f32x4 a0 = {0,0,0,0}, a1 = {0,0,0,0}, a2 = {0,0,0,0}, a3 = {0,0,0,0};
            const int ar = lane & 15, ac = (lane >> 4) * 8;
            #pragma unroll
            for (int kk = 0; kk < 32; kk += 4) {
                bf16x8 f0 = *(const bf16x8*)&a1cat[ar][ac + kk * 32];
                bf16x8 f1 = *(const bf16x8*)&a1cat[ar][ac + (kk + 1) * 32];
                bf16x8 f2 = *(const bf16x8*)&a1cat[ar][ac + (kk + 2) * 32];
                bf16x8 f3 = *(const bf16x8*)&a1cat[ar][ac + (kk + 3) * 32];
                a0 = __builtin_amdgcn_mfma_f32_16x16x32_bf16(f0, bi[kk],     a0, 0, 0, 0);
                a1 = __builtin_amdgcn_mfma_f32_16x16x32_bf16(f1, bi[kk + 1], a1, 0, 0, 0);
                a2 = __builtin_amdgcn_mfma_f32_16x16x32_bf16(f2, bi[kk + 2], a2, 0, 0, 0);
                a3 = __builtin_amdgcn_mfma_f32_16x16x32_bf16(f3, bi[kk + 3], a3, 0, 0, 0);
            }
            #pragma unroll
            for (int rr = 0; rr < 4; rr++) {
                int br = (lane >> 4) * 4 + rr;
                u32 me = f2bf((a0[rr] + a1[rr]) + (a2[rr] + a3[rr]) + bias);
                u32 ot = (u32)__shfl_xor((int)me, 1);
                if (br < 8 && !(lane & 1))
                    ST_AG(ring + ((size_t)(t & (RING - 1)) * B_ + bg * 8 + br) * 1024
                          + (gcol >> 1), me | (ot << 16));
            }
            __syncthreads();   // drain ring stores + protect a1cat
            if (tid == 0) ST_AG(sents + 256 + bg * 32 + gg, t + 1);
        }

    } else {
        // ================= role L2S: layer-2 scan =================
        const int bg = idx & 7, ug = (idx - 192) >> 3;
        const int gw = wave >> 1, uh = wave & 1;
        for (int j = tid; j < 8 * 260; j += 512) {
            int rw = 8 + j / 260, cl = (j % 260) * 2;
            *(u32*)&hl[rw][cl] = 0;
        }
        bf16x8 breg0[16], breg1[16];
        #pragma unroll
        for (int tt = 0; tt < 2; tt++) {
            const float* wr0 = Whh2
                + (size_t)(gw * H_ + ug * 64 + uh * 32 + tt * 16 + (lane & 15)) * H_
                + ((lane >> 4) * 8);
            #pragma unroll
            for (int kk = 0; kk < 16; kk++) {
                bf16x8 bb = pack8(wr0 + kk * 32);
                if (tt == 0) breg0[kk] = bb; else breg1[kk] = bb;
            }
        }
        const int bb_ = tid >> 6, uu = tid & 63;
        const int brow = bg * 8 + bb_, ucol = ug * 64 + uu;
        float c = c02[brow * H_ + ucol];
        #pragma unroll
        for (int j = 0; j < 8; ++j) {                    // tagged h0 publish
            int k = tid + j * 512;
            int prow = k >> 9, pcol = k & 511;
            ST_AG(hx2 + (size_t)(bg * 8 + prow) * H_ + pcol,
                  (1u << 16) | (u32)f2bf(h02[(bg * 8 + prow) * H_ + pcol]));
        }
        const int crow = tid >> 6, ccol = (tid & 63) * 8;
        __syncthreads();

        #pragma unroll 1
        for (int t = 0; t < T_; ++t) {
            if (tid < 16) {
                int* sp = sents + 256 + bg * 32 + tid;
                const int want = t + 1;
                int spin = 0;
                while (LD_AG(sp) < want) {
                    if (--budget < 0) break;
                    if (++spin > 2) __builtin_amdgcn_s_sleep(2);
                }
            }
            u64* src = (u64*)(hx2 + (size_t)(t & 1) * (B_ * H_)
                              + (size_t)(bg * 8 + crow) * H_ + ccol);
            const u32 wt = (u32)(t + 1);
            const u64 want = ((u64)wt << 16) | ((u64)wt << 48);
            u64 v0 = LD_AG(src + 0), v1 = LD_AG(src + 1);
            u64 v2 = LD_AG(src + 2), v3 = LD_AG(src + 3);
            int spin = 0;
            while ((((v0 ^ want) | (v1 ^ want) | (v2 ^ want) | (v3 ^ want)) & tmask) != 0) {
                if (--budget < 0) break;
                if (++spin > 2) __builtin_amdgcn_s_sleep(1);
                if ((v0 ^ want) & tmask) v0 = LD_AG(src + 0);
                if ((v1 ^ want) & tmask) v1 = LD_AG(src + 1);
                if ((v2 ^ want) & tmask) v2 = LD_AG(src + 2);
                if ((v3 ^ want) & tmask) v3 = LD_AG(src + 3);
            }
            u32x4 pk = { (u32)(v0 & 0xffff) | ((u32)(v0 >> 32) << 16),
                         (u32)(v1 & 0xffff) | ((u32)(v1 >> 32) << 16),
                         (u32)(v2 & 0xffff) | ((u32)(v2 >> 32) << 16),
                         (u32)(v3 & 0xffff) | ((u32)(v3 >> 32) << 16) };
            *(u32x4*)&hl[crow][ccol] = pk;
            __syncthreads();   // LDS ready + ring sentinel detected

            const size_t rb = ((size_t)(t & (RING - 1)) * B_ + brow) * 1024
                              + ug * 32 + (uu >> 1);
            u32 x0 = LD_AG(ring + rb);
            u32 x1 = LD_AG(ring + rb + 256);
            u32 x2 = LD_AG(ring + rb + 512);
            u32 x3 = LD_AG(ring + rb + 768);

            f32x4 a0 = {0,0,0,0}, a1 = {0,0,0,0}, a2 = {0,0,0,0}, a3 = {0,0,0,0};
            const int ar = lane & 15, ac = (lane >> 4) * 8;
            #pragma unroll
            for (int kk = 0; kk < 16; kk += 2) {
                bf16x8 f0 = *(const bf16x8*)&hl[ar][ac + kk * 32];
                bf16x8 f1 = *(const bf16x8*)&hl[ar][ac + (kk + 1) * 32];
                a0 = __builtin_amdgcn_mfma_f32_16x16x32_bf16(f0, breg0[kk],     a0, 0, 0, 0);
                a1 = __builtin_amdgcn_mfma_f32_16x16x32_bf16(f1, breg0[kk + 1], a1, 0, 0, 0);
                a2 = __builtin_amdgcn_mfma_f32_16x16x32_bf16(f0, breg1[kk],     a2, 0, 0, 0);
                a3 = __builtin_amdgcn_mfma_f32_16x16x32_bf16(f1, breg1[kk + 1], a3, 0, 0, 0);
            }
            #pragma unroll
            for (int rr = 0; rr < 4; rr++) {
                int br = (lane >> 4) * 4 + rr;
                if (br < 8) {
                    glds[gw][br][uh * 32 + (lane & 15)]      = a0[rr] + a1[rr];
                    glds[gw][br][uh * 32 + 16 + (lane & 15)] = a2[rr] + a3[rr];
                }
            }
            __syncthreads();   // glds ready; drains ring loads (vmcnt 0)
            if (tid == 0) ST_AG(sents + 512 + bg * 32 + ug, t + 1);  // progress

            const int sh = (uu & 1) * 16;
            float ip = glds[0][bb_][uu] + bf2f((u16)(x0 >> sh));
            float fp = glds[1][bb_][uu] + bf2f((u16)(x1 >> sh));
            float gp = glds[2][bb_][uu] + bf2f((u16)(x2 >> sh));
            float op = glds[3][bb_][uu] + bf2f((u16)(x3 >> sh));
            float gi = sigm(ip), gf = sigm(fp), gc = tanh_f(gp), go = sigm(op);
            c = gf * c + gi * gc;
            float h = go * tanh_f(c);
            u32 me = f2bf(h);
            ST_AG(hx2 + (size_t)((t + 1) & 1) * (B_ * H_) + (size_t)brow * H_ + ucol,
                  ((u32)(t + 2) << 16) | me);
            u32 ot = (u32)__shfl_xor((int)me, 1);
            if (!(uu & 1))
                h2pk[((size_t)brow * T_ + t) * 256 + (ucol >> 1)] = me | (ot << 16);
        }
    }
}

// --------------------------- FC (MFMA) + log_softmax -----------------------
__global__ __launch_bounds__(256) void fc_mfma(
    const u16* __restrict__ h2, const u16* __restrict__ Wfcp,   // (64,1024)
    const float* __restrict__ bfc, float* __restrict__ out)
{
    __shared__ u16 hl[16][1032];
    __shared__ float cl[16][68];
    const int tid = threadIdx.x, lane = tid & 63, wave = tid >> 6;
    const int r0 = blockIdx.x * 16;
    const int b = r0 >> 8;
    const int fr0 = (63 - b) * T_ + (r0 & 255);
    #pragma unroll
    for (int j = 0; j < 16; ++j) {
        int k = tid + j * 256;
        int row = k >> 8, c4 = k & 255;
        const u16* src = (c4 < 128)
            ? h2 + (size_t)(r0 + row) * H_ + c4 * 4
            : h2 + (size_t)(fr0 + row) * H_ + (c4 - 128) * 4;
        *(u64*)&hl[row][c4 * 4] = *(const u64*)src;
    }
    __syncthreads();
    const int ar = lane & 15, ac = (lane >> 4) * 8;
    const u16* wrow = Wfcp + (size_t)(wave * 16 + ar) * 1024 + ac;
    f32x4 a0 = {0,0,0,0}, a1 = {0,0,0,0};
    #pragma unroll
    for (int kk = 0; kk < 32; kk += 2) {
        bf16x8 f0 = *(const bf16x8*)&hl[ar][ac + kk * 32];
        bf16x8 f1 = *(const bf16x8*)&hl[ar][ac + (kk + 1) * 32];
        bf16x8 w0 = *(const bf16x8*)(wrow + kk * 32);
        bf16x8 w1 = *(const bf16x8*)(wrow + (kk + 1) * 32);
        a0 = __builtin_amdgcn_mfma_f32_16x16x32_bf16(f0, w0, a0, 0, 0, 0);
        a1 = __builtin_amdgcn_mfma_f32_16x16x32_bf16(f1, w1, a1, 0, 0, 0);
    }
    #pragma unroll
    for (int rr = 0; rr < 4; rr++)
        cl[(lane >> 4) * 4 + rr][wave * 16 + ar] = a0[rr] + a1[rr];
    __syncthreads();
    #pragma unroll
    for (int rr2 = 0; rr2 < 4; rr2++) {
        int row = wave * 4 + rr2;
        float acc = (lane < O_) ? cl[row][lane] + bfc[lane] : -1e30f;
        float m = acc;
        #pragma unroll
        for (int off = 32; off > 0; off >>= 1) m = fmaxf(m, __shfl_xor(m, off));
        float e = (lane < O_) ? __expf(acc - m) : 0.f;
        float sm = e;
        #pragma unroll
        for (int off = 32; off > 0; off >>= 1) sm += __shfl_xor(sm, off);
        float lse = m + __logf(sm);
        if (lane < O_) out[(size_t)(r0 + row) * O_ + lane] = acc - lse;
    }
}

// ------------------------------ launcher -----------------------------------

extern "C" void kernel_launch(void* const* d_in, const int* in_sizes, int n_in,
                              void* d_out, int out_size, void* d_ws, size_t ws_size,
                              hipStream_t stream)
{
    (void)in_sizes; (void)n_in; (void)out_size;
    const int*   x    = (const int*)  d_in[0];
    const float* emb  = (const float*)d_in[1];
    const float* Wih1 = (const float*)d_in[2];
    const float* Whh1 = (const float*)d_in[3];
    const float* b1   = (const float*)d_in[4];
    const float* h01  = (const float*)d_in[5];
    const float* c01  = (const float*)d_in[6];
    const float* Wih2 = (const float*)d_in[7];
    const float* Whh2 = (const float*)d_in[8];
    const float* b2   = (const float*)d_in[9];
    const float* h02  = (const float*)d_in[10];
    const float* c02  = (const float*)d_in[11];
    const float* Wfc  = (const float*)d_in[12];
    const float* bfc  = (const float*)d_in[13];
    float* out = (float*)d_out;

    char* ws = (char*)d_ws;
    size_t off = 0;
    auto alloc = [&](size_t bytes) {
        char* p = ws + off; off += (bytes + 255) & ~(size_t)255; return p;
    };
    u16* Wfcp  = (u16*)alloc((size_t)64 * 1024 * 2);          //   0.13 MB
    u16* xgb   = (u16*)alloc((size_t)NROW * G_ * 2);          //  67.11 MB
    u32* h1pub = (u32*)alloc((size_t)NROW * 256 * 4);         //  16.78 MB
    u32* ring  = (u32*)alloc((size_t)RING * B_ * 1024 * 4);   //   4.19 MB
    u32* hx1   = (u32*)alloc((size_t)2 * B_ * H_ * 4);        //   0.26 MB
    u32* hx2   = (u32*)alloc((size_t)2 * B_ * H_ * 4);        //   0.26 MB
    u32* h2pk  = (u32*)alloc((size_t)NROW * 256 * 4);         //  16.78 MB
    int* sents = (int*)alloc(768 * sizeof(int));              //   3 KB
    if (off > ws_size) return;   // clean diagnostic failure, never OOB

    hipMemsetAsync(sents, 0, 768 * sizeof(int), stream);
    wfc_pad<<<64, 256, 0, stream>>>(Wfc, Wfcp);

    gemm_fused<<<dim3(G_ / 128, NROW / 128), 256, 0, stream>>>(
        x, emb, Wih1, b1, xgb);

    scan12<<<256, 512, 0, stream>>>(xgb, Whh1, h01, c01, h1pub, hx1,
                                    Wih2, Whh2, b2, h02, c02, ring, hx2, h2pk,
                                    sents);

    fc_mfma<<<NROW / 16, 256, 0, stream>>>((const u16*)h2pk, Wfcp, bfc, out);
}